// Round 2
// baseline (87.940 us; speedup 1.0000x reference)
//
#include <hip/hip_runtime.h>

#define NB_IMG   2048
#define GSQ      169                 // 13*13
#define NCELLS   (NB_IMG * GSQ)
#define NCH      125
#define NANCH    5
#define BATCH_FLOATS (NCH * GSQ)     // 21125
#define ANCH_FLOATS  (25 * GSQ)      // 4225
#define STAGE_F4     1057            // float4s per staged (aligned) anchor slab

// Accumulator layout in d_ws (16 doubles):
// [0..3]  coord sq sums   [4] conf sq (obj)   [5] conf sq (noobj)
// [6..10] per-anchor class sq sums   [11..15] per-anchor obj counts

__global__ __launch_bounds__(256) void detloss_main(
    const float* __restrict__ det,
    const float* __restrict__ gt,
    const float* __restrict__ aw,
    const float* __restrict__ ah,
    double* __restrict__ acc)
{
    __shared__ float dstage[4232];   // 4225 + up-to-3 lead + pad to x4
    __shared__ float gstage[4232];
    __shared__ float part[4][16];

    const int b    = blockIdx.x;
    const int tid  = threadIdx.x;
    const int cell = tid;            // compute-active iff cell < 169

    float S0 = 0.f, S1 = 0.f, S2 = 0.f, S3 = 0.f;   // coord
    float S4 = 0.f, S5 = 0.f;                       // conf obj / noobj
    float Scls[NANCH] = {0.f, 0.f, 0.f, 0.f, 0.f};
    float Ccnt[NANCH] = {0.f, 0.f, 0.f, 0.f, 0.f};

    float awr[NANCH], ahr[NANCH];
    #pragma unroll
    for (int k = 0; k < NANCH; ++k) { awr[k] = aw[k]; ahr[k] = ah[k]; }

    // anchor-0 box values, kept in registers across anchors
    float px = 0.f, py = 0.f, dw = 0.f, dh = 0.f;
    float gx = 0.f, gy = 0.f, gw = 0.f, gh = 0.f, a2g = 0.f;

    const size_t bbase = (size_t)b * BATCH_FLOATS;

    #pragma unroll 1
    for (int k = 0; k < NANCH; ++k) {
        const size_t s0  = bbase + (size_t)k * ANCH_FLOATS; // region start (floats)
        const size_t A   = s0 & ~(size_t)3;                 // 16B-aligned down
        const int    off = (int)(s0 - A);                   // 0..3
        const float4* dg4 = (const float4*)det + (A >> 2);
        const float4* gg4 = (const float4*)gt  + (A >> 2);

        __syncthreads();   // previous compute phase done before overwrite
        #pragma unroll
        for (int i = 0; i < 5; ++i) {
            const int idx = tid + i * 256;
            if (idx < STAGE_F4) {
                const float4 v = dg4[idx];
                const float4 w = gg4[idx];
                *(float4*)&dstage[idx * 4] = v;
                *(float4*)&gstage[idx * 4] = w;
            }
        }
        __syncthreads();   // staged data visible

        if (cell < GSQ) {
            const float* dk = dstage + off;   // channel c of this anchor at dk[c*GSQ+cell]
            const float* gk = gstage + off;

            if (k == 0) {
                px = dk[0 * GSQ + cell]; py = dk[1 * GSQ + cell];
                dw = dk[2 * GSQ + cell]; dh = dk[3 * GSQ + cell];
                gx = gk[0 * GSQ + cell]; gy = gk[1 * GSQ + cell];
                gw = gk[2 * GSQ + cell]; gh = gk[3 * GSQ + cell];
                a2g = (gw - gx + 1.0f) * (gh - gy + 1.0f);
            }

            const float pw = dw * awr[k];
            const float ph = dh * ahr[k];
            const float x1 = fmaxf(px, gx);
            const float y1 = fmaxf(py, gy);
            const float x2 = fminf(pw, gw);
            const float y2 = fminf(ph, gh);
            const float inter = (x2 - x1 + 1.0f) * (y2 - y1 + 1.0f);
            const float a1    = (pw - px + 1.0f) * (ph - py + 1.0f);
            const float iou   = inter / (a1 + a2g - inter);

            const float g4v  = gk[4 * GSQ + cell];
            const float conf = dk[4 * GSQ + cell] * (iou >= 0.0f ? iou : 0.0f); // NaN->0
            const float d4   = conf - g4v;
            const float d4sq = d4 * d4;
            const bool  obj  = (g4v == 1.0f);
            const float m    = obj ? 1.0f : 0.0f;

            float dd;
            dd = dk[0 * GSQ + cell] - gk[0 * GSQ + cell]; S0 += m * dd * dd;
            dd = dk[1 * GSQ + cell] - gk[1 * GSQ + cell]; S1 += m * dd * dd;
            dd = dk[2 * GSQ + cell] - gk[2 * GSQ + cell]; S2 += m * dd * dd;
            dd = dk[3 * GSQ + cell] - gk[3 * GSQ + cell]; S3 += m * dd * dd;

            S4 += obj ? d4sq : 0.0f;   // selects, not mask-mul: avoid inf*0
            S5 += obj ? 0.0f : d4sq;

            float sc = 0.0f;
            #pragma unroll
            for (int j = 0; j < 20; ++j) {
                dd = dk[(5 + j) * GSQ + cell] - gk[(5 + j) * GSQ + cell];
                sc += dd * dd;
            }
            Scls[k] += m * sc;
            Ccnt[k] += m;
        }
    }

    // ---- block reduction of 16 partials ----
    float vals[16] = {S0, S1, S2, S3, S4, S5,
                      Scls[0], Scls[1], Scls[2], Scls[3], Scls[4],
                      Ccnt[0], Ccnt[1], Ccnt[2], Ccnt[3], Ccnt[4]};

    #pragma unroll
    for (int i = 0; i < 16; ++i) {
        #pragma unroll
        for (int off2 = 32; off2 > 0; off2 >>= 1)
            vals[i] += __shfl_down(vals[i], off2, 64);
    }

    const int wave = threadIdx.x >> 6;
    const int lane = threadIdx.x & 63;
    if (lane == 0) {
        #pragma unroll
        for (int i = 0; i < 16; ++i) part[wave][i] = vals[i];
    }
    __syncthreads();
    if (threadIdx.x < 16) {
        const float s = part[0][threadIdx.x] + part[1][threadIdx.x] +
                        part[2][threadIdx.x] + part[3][threadIdx.x];
        atomicAdd(&acc[threadIdx.x], (double)s);
    }
}

__global__ void detloss_final(const double* __restrict__ acc, float* __restrict__ out)
{
    if (threadIdx.x == 0 && blockIdx.x == 0) {
        const double cnt = acc[11] + acc[12] + acc[13] + acc[14] + acc[15];
        const double coord = (cnt > 0.0) ? (acc[0] + acc[1] + acc[2] + acc[3]) / cnt : 0.0;
        const double s4    = (cnt > 0.0) ? acc[4] / cnt : 0.0;
        const double obj_loss = 5.0 * coord + s4;

        const double cntno  = (double)NCELLS * (double)NANCH - cnt;
        const double no_obj = (cntno > 0.0) ? 0.5 * acc[5] / cntno : 0.0;

        double confsum = 0.0;
        for (int k = 0; k < NANCH; ++k) {
            const double ck = acc[11 + k];
            if (ck > 0.0) confsum += acc[6 + k] / ck;
        }
        const double loss = obj_loss + no_obj + confsum;
        out[0] = (float)loss;
        out[1] = (float)obj_loss;
        out[2] = (float)no_obj;
        out[3] = (float)confsum;
    }
}

extern "C" void kernel_launch(void* const* d_in, const int* in_sizes, int n_in,
                              void* d_out, int out_size, void* d_ws, size_t ws_size,
                              hipStream_t stream)
{
    const float* det = (const float*)d_in[0];
    const float* gt  = (const float*)d_in[1];
    const float* aw  = (const float*)d_in[2];
    const float* ah  = (const float*)d_in[3];
    double* acc = (double*)d_ws;
    float*  out = (float*)d_out;

    hipMemsetAsync(acc, 0, 16 * sizeof(double), stream);
    detloss_main<<<NB_IMG, 256, 0, stream>>>(det, gt, aw, ah, acc);
    detloss_final<<<1, 64, 0, stream>>>(acc, out);
}